// Round 8
// baseline (174.974 us; speedup 1.0000x reference)
//
#include <hip/hip_runtime.h>

#define BATCH 64
#define SEQ   512
#define JDIM  96
#define TN    64
#define KC    64
#define NCH   (SEQ / KC)
#define LDB   72    // Bs row stride (ushort): 144 B -> even bank spread on frag reads
#define LOG2D (-0.32192809489f)   // log2(0.8)

typedef __attribute__((ext_vector_type(8))) short bf16x8;
typedef __attribute__((ext_vector_type(4))) float f32x4;

// exact RNE float->bf16 (finite inputs)
__device__ __forceinline__ unsigned short f2bf(float f) {
  unsigned u = __float_as_uint(f);
  u += 0x7FFFu + ((u >> 16) & 1u);
  return (unsigned short)(u >> 16);
}

// async global->LDS DMA, 16 B per lane; lds dst = wave-uniform base + lane*16
__device__ __forceinline__ void dma16(void* lds, const void* g) {
  __builtin_amdgcn_global_load_lds(
      (const __attribute__((address_space(1))) unsigned*)g,
      (__attribute__((address_space(3))) unsigned*)lds, 16, 0, 0);
}

// workgroup barrier that waits LDS ops only (does NOT drain vmcnt -> DMA stays in flight)
#define LGKM_BARRIER() do {                                  \
  asm volatile("s_waitcnt lgkmcnt(0)" ::: "memory");         \
  __builtin_amdgcn_s_barrier();                              \
  asm volatile("" ::: "memory");                             \
} while (0)

// ---------------- T1: xT[j][b*SEQ+m] = bf16(x[b][m][j])
__global__ __launch_bounds__(256) void transpose_in_kernel(
    const float* __restrict__ x, unsigned short* __restrict__ xT) {
  __shared__ float tile[JDIM * 65];  // [j][rr]
  const int r0 = blockIdx.x * 64;    // 512 blocks cover R = 32768 rows
  const int R = BATCH * SEQ;
  for (int idx = threadIdx.x; idx < 64 * 24; idx += 256) {
    int rr = idx / 24, jg = idx - rr * 24;
    float4 v = *(const float4*)(x + (size_t)(r0 + rr) * JDIM + 4 * jg);
    tile[(4 * jg + 0) * 65 + rr] = v.x;
    tile[(4 * jg + 1) * 65 + rr] = v.y;
    tile[(4 * jg + 2) * 65 + rr] = v.z;
    tile[(4 * jg + 3) * 65 + rr] = v.w;
  }
  __syncthreads();
  for (int idx = threadIdx.x; idx < JDIM * 8; idx += 256) {
    int jj = idx >> 3, rg = idx & 7;
    const float* t = &tile[jj * 65 + 8 * rg];
    uint4 pk;
    pk.x = (unsigned)f2bf(t[0]) | ((unsigned)f2bf(t[1]) << 16);
    pk.y = (unsigned)f2bf(t[2]) | ((unsigned)f2bf(t[3]) << 16);
    pk.z = (unsigned)f2bf(t[4]) | ((unsigned)f2bf(t[5]) << 16);
    pk.w = (unsigned)f2bf(t[6]) | ((unsigned)f2bf(t[7]) << 16);
    *(uint4*)(&xT[(size_t)jj * R + r0 + 8 * rg]) = pk;
  }
}

// ---------------- Fused, async-DMA double-buffered:
// per block (j, n-tile 64): C[64b x 64n] = X_j * exp(pre_analytic + off)^T via MFMA, /L.
// Chunk ch+1's A (bf16 xT) and raw O (fp32 off) are DMA'd into the idle LDS buffer while
// chunk ch computes; only the top __syncthreads drains vmcnt. XOR-swizzled layouts keep
// LDS reads bank-even. Bs (bf16 exp) is built in place inside the consumed O buffer.
__global__ __launch_bounds__(256, 3) void fused_kernel(
    const unsigned short* __restrict__ xT,  // [J][B*SEQ] bf16
    const float* __restrict__ off,          // [J][SEQ][SEQ]
    float* __restrict__ outT) {             // [J][SEQ][B]
  __shared__ __align__(16) unsigned short Araw[2][BATCH * KC];  // 2 x 8 KB, swizzled g^=r&7
  __shared__ __align__(16) float Oraw[2][TN * KC];              // 2 x 16 KB, swizzled g^=r&15
  __shared__ float Linv[TN];

  const int j  = blockIdx.x >> 3;
  const int n0 = (blockIdx.x & 7) * TN;

  const int tid  = threadIdx.x;
  const int lane = tid & 63;
  const int wid  = tid >> 6;
  const int ln   = lane & 15;
  const int quad = lane >> 4;
  const int bw   = (wid & 1) * 32;
  const int nw   = (wid >> 1) * 32;

  const unsigned short* xTj = xT + (size_t)j * (BATCH * SEQ);
  const float* offj = off + (size_t)j * (SEQ * SEQ);

  // DMA lane geometry (per-lane swizzled gather sources, per-wave uniform LDS bases)
  const unsigned short* pA[2];
  int aoff[2];
#pragma unroll
  for (int t = 0; t < 2; ++t) {
    const int r = 8 * (2 * wid + t) + (lane >> 3);
    const int g = (lane & 7) ^ (r & 7);
    pA[t] = xTj + (size_t)r * SEQ + 8 * g;
    aoff[t] = (2 * wid + t) * 1024;   // bytes
  }
  const float* pO[4];
  int ooff[4];
#pragma unroll
  for (int t = 0; t < 4; ++t) {
    const int r = 4 * (4 * wid + t) + (lane >> 4);
    const int g = (lane & 15) ^ (r & 15);
    pO[t] = offj + (size_t)(n0 + r) * SEQ + 4 * g;
    ooff[t] = (4 * wid + t) * 1024;   // bytes
  }

  // prologue: DMA chunk 0 into buffer 0
#pragma unroll
  for (int t = 0; t < 2; ++t) dma16((char*)&Araw[0][0] + aoff[t], pA[t]);
#pragma unroll
  for (int t = 0; t < 4; ++t) dma16((char*)&Oraw[0][0] + ooff[t], pO[t]);

  f32x4 acc[2][2];
#pragma unroll
  for (int i = 0; i < 2; ++i)
#pragma unroll
    for (int q = 0; q < 2; ++q) acc[i][q] = (f32x4){0.f, 0.f, 0.f, 0.f};

  const int nl  = tid >> 2;          // exp-phase row (0..63)
  const int sub = tid & 3;           // 16-float k-slice within the row
  const int nglob = n0 + nl;
  const float cn = 0.2f / (1.0f - exp2f(LOG2D * (float)(nglob + 1)));
  float Lpart = 0.f;

  for (int ch = 0; ch < NCH; ++ch) {
    const int c = ch & 1;
    __syncthreads();                 // drains DMA(ch) (the only outstanding vmcnt)

    if (ch + 1 < NCH) {              // launch DMA(ch+1) into the idle buffer
#pragma unroll
      for (int t = 0; t < 2; ++t) { pA[t] += KC; dma16((char*)&Araw[c ^ 1][0] + aoff[t], pA[t]); }
#pragma unroll
      for (int t = 0; t < 4; ++t) { pO[t] += KC; dma16((char*)&Oraw[c ^ 1][0] + ooff[t], pO[t]); }
    }

    // ---- exp phase: read raw off (swizzle-corrected), compute exp(off + analytic pre)
    const char* Ob = (const char*)&Oraw[c][0];
    float4 o4[4];
#pragma unroll
    for (int e = 0; e < 4; ++e) {
      const int gs = (4 * sub + e) ^ (nl & 15);
      o4[e] = *(const float4*)(Ob + nl * 256 + gs * 16);
    }
    // A fragments for this chunk (swizzle-corrected); independent of Bs
    bf16x8 af[2][2];
#pragma unroll
    for (int ksI = 0; ksI < 2; ++ksI)
#pragma unroll
      for (int i = 0; i < 2; ++i) {
        const int row = bw + 16 * i + ln;
        const int gs = ((ksI << 2) + quad) ^ (ln & 7);
        af[ksI][i] = *(const bf16x8*)((const char*)&Araw[c][0] + row * 128 + gs * 16);
      }
    const int m0 = ch * KC;
    const int d0 = nglob - (m0 + 16 * sub);
    float p = cn * exp2f(LOG2D * (float)(d0 < 0 ? 0 : d0));  // 0.8^d chain start
    float ex[16];
    float ls = 0.f;
#pragma unroll
    for (int e = 0; e < 4; ++e) {
      const float* ov = (const float*)&o4[e];
#pragma unroll
      for (int i = 0; i < 4; ++i) {
        const int q = 4 * e + i;
        const float pr = (d0 - q >= 0) ? p : 0.f;
        p *= 1.25f;                                           // 0.8^(d-1) = 0.8^d * 1.25
        const float v = __expf(ov[i] + pr);
        ex[q] = v;
        ls += v;
      }
    }
    Lpart += ls;

    LGKM_BARRIER();   // all raw-O reads retired -> safe to overwrite in place

    unsigned short* Bs = (unsigned short*)&Oraw[c][0];        // Bs aliases consumed O buffer
    uint4 pk0, pk1;
    pk0.x = (unsigned)f2bf(ex[0])  | ((unsigned)f2bf(ex[1])  << 16);
    pk0.y = (unsigned)f2bf(ex[2])  | ((unsigned)f2bf(ex[3])  << 16);
    pk0.z = (unsigned)f2bf(ex[4])  | ((unsigned)f2bf(ex[5])  << 16);
    pk0.w = (unsigned)f2bf(ex[6])  | ((unsigned)f2bf(ex[7])  << 16);
    pk1.x = (unsigned)f2bf(ex[8])  | ((unsigned)f2bf(ex[9])  << 16);
    pk1.y = (unsigned)f2bf(ex[10]) | ((unsigned)f2bf(ex[11]) << 16);
    pk1.z = (unsigned)f2bf(ex[12]) | ((unsigned)f2bf(ex[13]) << 16);
    pk1.w = (unsigned)f2bf(ex[14]) | ((unsigned)f2bf(ex[15]) << 16);
    *(uint4*)(Bs + nl * LDB + 16 * sub)     = pk0;
    *(uint4*)(Bs + nl * LDB + 16 * sub + 8) = pk1;

    LGKM_BARRIER();   // Bs visible to all waves

    // ---- MFMA phase
#pragma unroll
    for (int ksI = 0; ksI < 2; ++ksI) {
      bf16x8 bfr[2];
#pragma unroll
      for (int q = 0; q < 2; ++q)
        bfr[q] = *(const bf16x8*)(Bs + (nw + 16 * q + ln) * LDB + 32 * ksI + 8 * quad);
#pragma unroll
      for (int i = 0; i < 2; ++i)
#pragma unroll
        for (int q = 0; q < 2; ++q)
          acc[i][q] = __builtin_amdgcn_mfma_f32_16x16x32_bf16(af[ksI][i], bfr[q], acc[i][q], 0, 0, 0);
    }
  }

  // ---- L reduction (Lred aliases dead A buffer)
  __syncthreads();
  float* Lred = (float*)&Araw[0][0];
  Lred[nl * 5 + sub] = Lpart;
  __syncthreads();
  if (tid < TN) {
    const float s = (Lred[tid * 5 + 0] + Lred[tid * 5 + 1]) +
                    (Lred[tid * 5 + 2] + Lred[tid * 5 + 3]);
    Linv[tid] = 1.0f / s;
  }
  __syncthreads();

  // ---- epilogue: C/D layout col(=n)=lane&15, row(=b)=quad*4+reg -> float4 along b
  float* outTj = outT + (size_t)j * (SEQ * BATCH);
#pragma unroll
  for (int q = 0; q < 2; ++q) {
    const int nc = nw + 16 * q + ln;
    const float linv = Linv[nc];
#pragma unroll
    for (int i = 0; i < 2; ++i) {
      float4 v;
      v.x = acc[i][q][0] * linv;
      v.y = acc[i][q][1] * linv;
      v.z = acc[i][q][2] * linv;
      v.w = acc[i][q][3] * linv;
      *(float4*)(&outTj[(size_t)(n0 + nc) * BATCH + bw + 16 * i + 4 * quad]) = v;
    }
  }
}

// ---------------- T2: out[b][n][j] = outT[j][n][b]
__global__ __launch_bounds__(256) void transpose_out_kernel(
    const float* __restrict__ outT, float* __restrict__ out) {
  __shared__ float tile[JDIM * 65];  // [j][b]
  const int n = blockIdx.x;          // 512 blocks
  for (int idx = threadIdx.x; idx < JDIM * 16; idx += 256) {
    int jj = idx >> 4, g = idx & 15;
    float4 v = *(const float4*)(outT + ((size_t)jj * SEQ + n) * BATCH + 4 * g);
    float* t = &tile[jj * 65 + 4 * g];
    t[0] = v.x; t[1] = v.y; t[2] = v.z; t[3] = v.w;
  }
  __syncthreads();
  for (int idx = threadIdx.x; idx < BATCH * 24; idx += 256) {
    int b = idx / 24, jg = idx - b * 24;
    float4 w;
    w.x = tile[(4 * jg + 0) * 65 + b];
    w.y = tile[(4 * jg + 1) * 65 + b];
    w.z = tile[(4 * jg + 2) * 65 + b];
    w.w = tile[(4 * jg + 3) * 65 + b];
    *(float4*)(out + ((size_t)b * SEQ + n) * JDIM + 4 * jg) = w;
  }
}

extern "C" void kernel_launch(void* const* d_in, const int* in_sizes, int n_in,
                              void* d_out, int out_size, void* d_ws, size_t ws_size,
                              hipStream_t stream) {
  const float* x   = (const float*)d_in[0];  // [64, 512, 96]
  const float* off = (const float*)d_in[1];  // [96, 512, 512]
  float* out = (float*)d_out;                // [64, 512, 96]

  unsigned short* xT = (unsigned short*)d_ws;                 // bf16 [96][64*512] = 6.29 MB
  float* outT = (float*)((char*)d_ws + (size_t)JDIM * BATCH * SEQ * sizeof(unsigned short));
                                                              // f32 [96][512][64] = 12.58 MB

  transpose_in_kernel<<<BATCH * SEQ / 64, 256, 0, stream>>>(x, xT);
  fused_kernel<<<JDIM * (SEQ / TN), 256, 0, stream>>>(xT, off, outT);
  transpose_out_kernel<<<SEQ, 256, 0, stream>>>(outT, out);
}